// Round 1
// baseline (790.816 us; speedup 1.0000x reference)
//
#include <hip/hip_runtime.h>
#include <hip/hip_bf16.h>
#include <cstdint>
#include <cstddef>

#define NN 100000      // nodes
#define NE 1600000     // edges
#define HH 128         // hidden dim
#define NG 256         // graphs

typedef __bf16 bf16x8 __attribute__((ext_vector_type(8)));
typedef float floatx4 __attribute__((ext_vector_type(4)));

__device__ __forceinline__ uint32_t f2b(float f) {
  union { float f; uint32_t u; } v; v.f = f;
  uint32_t u = v.u;
  return (u + 0x7FFFu + ((u >> 16) & 1u)) >> 16;   // RNE to bf16 (raw 16 bits)
}
__device__ __forceinline__ float b2f(uint32_t h) {
  union { uint32_t u; float f; } v; v.u = h << 16;
  return v.f;
}

// ---------------- CSR build ----------------
__global__ void k_hist(const int* __restrict__ dst, int* __restrict__ cnt) {
  int e = blockIdx.x * 256 + threadIdx.x;
  if (e < NE) atomicAdd(&cnt[dst[e]], 1);
}

__global__ void k_scan1(const int* __restrict__ cnt, int* __restrict__ off,
                        int* __restrict__ bsum) {
  __shared__ int s[256];
  int t = threadIdx.x;
  int i = blockIdx.x * 256 + t;
  int x = (i < NN) ? cnt[i] : 0;
  s[t] = x; __syncthreads();
  for (int d = 1; d < 256; d <<= 1) {
    int v = (t >= d) ? s[t - d] : 0;
    __syncthreads();
    s[t] += v;
    __syncthreads();
  }
  if (i < NN) off[i] = s[t] - x;            // block-local exclusive
  if (t == 255) bsum[blockIdx.x] = s[255];  // block total
}

__global__ void k_scan2(int* __restrict__ bsum, int nb) {
  __shared__ int s[512];
  int t = threadIdx.x;
  int x = (t < nb) ? bsum[t] : 0;
  s[t] = x; __syncthreads();
  for (int d = 1; d < 512; d <<= 1) {
    int v = (t >= d) ? s[t - d] : 0;
    __syncthreads();
    s[t] += v;
    __syncthreads();
  }
  if (t < nb) bsum[t] = s[t] - x;           // exclusive block offsets
}

__global__ void k_scan3(int* __restrict__ off, const int* __restrict__ bsum,
                        int* __restrict__ cur) {
  int i = blockIdx.x * 256 + threadIdx.x;
  if (i < NN) {
    int v = off[i] + bsum[blockIdx.x];
    off[i] = v;
    cur[i] = v;
  }
  if (i == 0) off[NN] = NE;
}

__global__ void k_inv(const int* __restrict__ cnt, float* __restrict__ inv) {
  int i = blockIdx.x * 256 + threadIdx.x;
  if (i < NN) inv[i] = rsqrtf((float)cnt[i] + 1.0f);   // +1 self loop
}

__global__ void k_scatter(const int* __restrict__ src, const int* __restrict__ dst,
                          int* __restrict__ cur, int* __restrict__ csrs) {
  int e = blockIdx.x * 256 + threadIdx.x;
  if (e < NE) {
    int d = dst[e];
    int p = atomicAdd(&cur[d], 1);
    csrs[p] = src[e];
  }
}

// ---------------- fp32 -> bf16 convert ----------------
__global__ void k_cvt(const float* __restrict__ x, uint16_t* __restrict__ xb) {
  size_t i = ((size_t)blockIdx.x * 256 + threadIdx.x) * 4;
  if (i >= (size_t)NN * HH) return;
  float4 v = *(const float4*)(x + i);
  uint2 o;
  o.x = f2b(v.x) | (f2b(v.y) << 16);
  o.y = f2b(v.z) | (f2b(v.w) << 16);
  *(uint2*)(xb + i) = o;
}

// ---------------- GEMM: Out[M,128] = bf16( A[M,128] @ W[128,128] + bias ) ----------------
// 256 thr = 4 waves; block tile 128 rows; wave tile 32 rows x 128 cols.
// mfma_f32_16x16x32_bf16: A[m=lane&15][k=(lane>>4)*8+j]; B[k][n=lane&15];
// C row=(lane>>4)*4+reg, col=lane&15  (m89/m120-verified layouts)
__global__ __launch_bounds__(256) void k_gemm(
    const uint16_t* __restrict__ A, const float* __restrict__ W,
    const float* __restrict__ bias, uint16_t* __restrict__ Out,
    int M, int do_relu)
{
  __shared__ uint16_t Wt[128][136];   // W transposed: Wt[n][k], +8 pad (16B) vs bank conflicts
  const int tid = threadIdx.x;

  // stage W^T (fp32 global -> bf16 LDS). task idx: n = idx&127, kgroup = idx>>7 (4 k's)
  for (int it = 0; it < 16; ++it) {
    int idx = tid + it * 256;
    int n = idx & 127;
    int k0 = (idx >> 7) * 4;
    uint2 wv;
    wv.x = f2b(W[(k0 + 0) * 128 + n]) | (f2b(W[(k0 + 1) * 128 + n]) << 16);
    wv.y = f2b(W[(k0 + 2) * 128 + n]) | (f2b(W[(k0 + 3) * 128 + n]) << 16);
    *(uint2*)&Wt[n][k0] = wv;
  }
  __syncthreads();

  const int lane = tid & 63;
  const int wave = tid >> 6;
  const int lrow = lane & 15;
  const int lk = (lane >> 4) * 8;
  const int row0 = blockIdx.x * 128 + wave * 32;

  floatx4 acc[2][8];
#pragma unroll
  for (int t = 0; t < 2; ++t)
#pragma unroll
    for (int n = 0; n < 8; ++n)
      acc[t][n] = (floatx4){0.f, 0.f, 0.f, 0.f};

#pragma unroll
  for (int ks = 0; ks < 4; ++ks) {
    bf16x8 a[2];
#pragma unroll
    for (int t = 0; t < 2; ++t) {
      int r = row0 + t * 16 + lrow;
      uint4 tmp = {0u, 0u, 0u, 0u};
      if (r < M) tmp = *(const uint4*)(A + (size_t)r * HH + ks * 32 + lk);
      a[t] = __builtin_bit_cast(bf16x8, tmp);
    }
#pragma unroll
    for (int n = 0; n < 8; ++n) {
      bf16x8 b = __builtin_bit_cast(bf16x8, *(const uint4*)&Wt[n * 16 + lrow][ks * 32 + lk]);
      acc[0][n] = __builtin_amdgcn_mfma_f32_16x16x32_bf16(a[0], b, acc[0][n], 0, 0, 0);
      acc[1][n] = __builtin_amdgcn_mfma_f32_16x16x32_bf16(a[1], b, acc[1][n], 0, 0, 0);
    }
  }

  float bc[8];
#pragma unroll
  for (int n = 0; n < 8; ++n) bc[n] = bias[n * 16 + lrow];

  const int rbase = (lane >> 4) * 4;
#pragma unroll
  for (int t = 0; t < 2; ++t) {
#pragma unroll
    for (int r = 0; r < 4; ++r) {
      int row = row0 + t * 16 + rbase + r;
      if (row < M) {
#pragma unroll
        for (int n = 0; n < 8; ++n) {
          float v = acc[t][n][r] + bc[n];
          if (do_relu) v = fmaxf(v, 0.f);
          Out[(size_t)row * HH + n * 16 + lrow] = (uint16_t)f2b(v);
        }
      }
    }
  }
}

// ---------------- aggregation: h'[i] = inv[i]*( sum_e inv[src]*hw[src] + inv[i]*hw[i] ) ----------------
// 32 threads per node, 4 channels each.
__global__ __launch_bounds__(256) void k_agg(
    const uint16_t* __restrict__ hw, const int* __restrict__ off,
    const int* __restrict__ csrs, const float* __restrict__ inv,
    uint16_t* __restrict__ hout, int do_relu)
{
  int node = blockIdx.x * 8 + (threadIdx.x >> 5);
  if (node >= NN) return;
  int c = (threadIdx.x & 31) * 4;

  float invd = inv[node];

  const uint2* sp = (const uint2*)(hw + (size_t)node * HH + c);
  uint2 sv = *sp;
  float a0 = invd * b2f(sv.x & 0xFFFFu);
  float a1 = invd * b2f(sv.x >> 16);
  float a2 = invd * b2f(sv.y & 0xFFFFu);
  float a3 = invd * b2f(sv.y >> 16);

  int e0 = off[node], e1 = off[node + 1];
  for (int e = e0; e < e1; ++e) {
    int s = csrs[e];
    float w = inv[s];
    uint2 v = *(const uint2*)(hw + (size_t)s * HH + c);
    a0 += w * b2f(v.x & 0xFFFFu);
    a1 += w * b2f(v.x >> 16);
    a2 += w * b2f(v.y & 0xFFFFu);
    a3 += w * b2f(v.y >> 16);
  }
  a0 *= invd; a1 *= invd; a2 *= invd; a3 *= invd;
  if (do_relu) {
    a0 = fmaxf(a0, 0.f); a1 = fmaxf(a1, 0.f);
    a2 = fmaxf(a2, 0.f); a3 = fmaxf(a3, 0.f);
  }
  uint2 o;
  o.x = f2b(a0) | (f2b(a1) << 16);
  o.y = f2b(a2) | (f2b(a3) << 16);
  *(uint2*)(hout + (size_t)node * HH + c) = o;
}

// ---------------- global add pool over sorted batch ids ----------------
__global__ void k_pool(const uint16_t* __restrict__ h, const int* __restrict__ batch,
                       float* __restrict__ pooled) {
  const int CHUNK = 256;
  int c = threadIdx.x;   // 128 threads, one channel each
  int i0 = blockIdx.x * CHUNK;
  if (i0 >= NN) return;
  int iend = min(i0 + CHUNK, NN);
  float acc = 0.f;
  int g = batch[i0];
  for (int i = i0; i < iend; ++i) {
    int gi = batch[i];
    if (gi != g) {
      atomicAdd(&pooled[g * HH + c], acc);
      acc = 0.f;
      g = gi;
    }
    acc += b2f((uint32_t)h[(size_t)i * HH + c]);
  }
  atomicAdd(&pooled[g * HH + c], acc);
}

// ---------------- decoder: out[g] = relu(pooled[g] @ W1 + b1) @ W2 + b2 ----------------
__global__ void k_dec(const float* __restrict__ pooled,
                      const float* __restrict__ w1, const float* __restrict__ b1,
                      const float* __restrict__ w2, const float* __restrict__ b2,
                      float* __restrict__ out) {
  __shared__ float p[128], t[128];
  int g = blockIdx.x, j = threadIdx.x;
  p[j] = pooled[g * HH + j];
  __syncthreads();
  float a = b1[j];
  for (int k = 0; k < 128; ++k) a += p[k] * w1[k * 128 + j];
  t[j] = fmaxf(a, 0.f);
  __syncthreads();
  if (j < 10) {
    float o = b2[j];
    for (int k = 0; k < 128; ++k) o += t[k] * w2[k * 10 + j];
    out[g * 10 + j] = o;
  }
}

extern "C" void kernel_launch(void* const* d_in, const int* in_sizes, int n_in,
                              void* d_out, int out_size, void* d_ws, size_t ws_size,
                              hipStream_t stream) {
  const float* x       = (const float*)d_in[0];
  const int*   eidx    = (const int*)d_in[1];
  const int*   src     = eidx;            // edge_index[0]
  const int*   dst     = eidx + NE;       // edge_index[1]
  const int*   batch   = (const int*)d_in[3];
  const float* enc_w1  = (const float*)d_in[4];
  const float* enc_b1  = (const float*)d_in[5];
  const float* enc_w2  = (const float*)d_in[6];
  const float* enc_b2  = (const float*)d_in[7];
  const float* conv_w  = (const float*)d_in[8];
  const float* conv_b  = (const float*)d_in[9];
  const float* dec_w1  = (const float*)d_in[10];
  const float* dec_b1  = (const float*)d_in[11];
  const float* dec_w2  = (const float*)d_in[12];
  const float* dec_b2  = (const float*)d_in[13];
  float* out = (float*)d_out;

  char* ws = (char*)d_ws;
  size_t o = 0;
  auto alloc = [&](size_t bytes) -> char* {
    char* p = ws + o;
    o += (bytes + 255) & ~(size_t)255;
    return p;
  };
  int*      cnt    = (int*)alloc((size_t)NN * 4);
  int*      off    = (int*)alloc((size_t)(NN + 1) * 4);
  int*      cur    = (int*)alloc((size_t)NN * 4);
  int*      bsum   = (int*)alloc(512 * 4);
  int*      csrs   = (int*)alloc((size_t)NE * 4);
  float*    inv    = (float*)alloc((size_t)NN * 4);
  float*    pooled = (float*)alloc((size_t)NG * HH * 4);
  uint16_t* buf0   = (uint16_t*)alloc((size_t)NN * HH * 2);
  uint16_t* buf1   = (uint16_t*)alloc((size_t)NN * HH * 2);

  hipMemsetAsync(cnt, 0, (size_t)NN * 4, stream);
  hipMemsetAsync(pooled, 0, (size_t)NG * HH * 4, stream);

  // CSR build (in-degree histogram -> exclusive scan -> counting scatter)
  k_hist<<<dim3((NE + 255) / 256), dim3(256), 0, stream>>>(dst, cnt);
  k_scan1<<<dim3((NN + 255) / 256), dim3(256), 0, stream>>>(cnt, off, bsum);
  k_scan2<<<dim3(1), dim3(512), 0, stream>>>(bsum, (NN + 255) / 256);
  k_scan3<<<dim3((NN + 255) / 256), dim3(256), 0, stream>>>(off, bsum, cur);
  k_inv<<<dim3((NN + 255) / 256), dim3(256), 0, stream>>>(cnt, inv);
  k_scatter<<<dim3((NE + 255) / 256), dim3(256), 0, stream>>>(src, dst, cur, csrs);

  // encoder
  k_cvt<<<dim3((NN * HH / 4 + 255) / 256), dim3(256), 0, stream>>>(x, buf0);
  const int GB = (NN + 127) / 128;   // 782
  k_gemm<<<dim3(GB), dim3(256), 0, stream>>>(buf0, enc_w1, enc_b1, buf1, NN, 1);
  k_gemm<<<dim3(GB), dim3(256), 0, stream>>>(buf1, enc_w2, enc_b2, buf0, NN, 0);

  // 3 GCN layers: gemm (b0->b1) then aggregate (b1->b0)
  k_gemm<<<dim3(GB), dim3(256), 0, stream>>>(buf0, conv_w + 0 * 16384, conv_b + 0,   buf1, NN, 0);
  k_agg <<<dim3(NN / 8), dim3(256), 0, stream>>>(buf1, off, csrs, inv, buf0, 1);
  k_gemm<<<dim3(GB), dim3(256), 0, stream>>>(buf0, conv_w + 1 * 16384, conv_b + 128, buf1, NN, 0);
  k_agg <<<dim3(NN / 8), dim3(256), 0, stream>>>(buf1, off, csrs, inv, buf0, 1);
  k_gemm<<<dim3(GB), dim3(256), 0, stream>>>(buf0, conv_w + 2 * 16384, conv_b + 256, buf1, NN, 0);
  k_agg <<<dim3(NN / 8), dim3(256), 0, stream>>>(buf1, off, csrs, inv, buf0, 0);

  // pool + decoder
  k_pool<<<dim3((NN + 255) / 256), dim3(128), 0, stream>>>(buf0, batch, pooled);
  k_dec<<<dim3(NG), dim3(128), 0, stream>>>(pooled, dec_w1, dec_b1, dec_w2, dec_b2, out);
}

// Round 2
// 681.419 us; speedup vs baseline: 1.1605x; 1.1605x over previous
//
#include <hip/hip_runtime.h>
#include <hip/hip_bf16.h>
#include <cstdint>
#include <cstddef>

#define NN 100000      // nodes
#define NE 1600000     // edges
#define HH 128         // hidden dim
#define NG 256         // graphs

#define NB 196         // buckets (512 nodes each; 196*512 = 100352 >= NN)
#define BSH 9          // bucket shift
#define BMSK 511
#define CHUNK 16384    // edges per binning block
#define NBLK 98        // ceil(NE / CHUNK)

typedef __bf16 bf16x8 __attribute__((ext_vector_type(8)));
typedef float floatx4 __attribute__((ext_vector_type(4)));

__device__ __forceinline__ uint32_t f2b(float f) {
  union { float f; uint32_t u; } v; v.f = f;
  uint32_t u = v.u;
  return (u + 0x7FFFu + ((u >> 16) & 1u)) >> 16;   // RNE to bf16 (raw 16 bits)
}
__device__ __forceinline__ float b2f(uint32_t h) {
  union { uint32_t u; float f; } v; v.u = h << 16;
  return v.f;
}

// ---------------- CSR build: two-pass LDS-binned counting sort ----------------
// Pass A: per-chunk bucket histogram
__global__ __launch_bounds__(256) void k_bin_count(const int* __restrict__ dst,
                                                   int* __restrict__ blkcnt) {
  __shared__ int h[NB];
  int t = threadIdx.x;
  if (t < NB) h[t] = 0;
  __syncthreads();
  int base = blockIdx.x * CHUNK;
  int end = min(base + CHUNK, NE);
  for (int i = base + t; i < end; i += 256)
    atomicAdd(&h[dst[i] >> BSH], 1);
  __syncthreads();
  if (t < NB) blkcnt[blockIdx.x * NB + t] = h[t];
}

// Pass B: table build — global placement offsets so pairbuf is bucket-contiguous
__global__ void k_btable(const int* __restrict__ blkcnt, int* __restrict__ poff,
                         int* __restrict__ gbase, int* __restrict__ off) {
  __shared__ int tot[NB];
  __shared__ int gb[NB + 1];
  int t = threadIdx.x;
  if (t < NB) {
    int acc = 0;
    for (int r = 0; r < NBLK; ++r) {
      poff[r * NB + t] = acc;        // column-wise exclusive scan (local)
      acc += blkcnt[r * NB + t];
    }
    tot[t] = acc;
  }
  __syncthreads();
  if (t == 0) {
    int acc = 0;
    for (int b = 0; b < NB; ++b) { gb[b] = acc; gbase[b] = acc; acc += tot[b]; }
    gb[NB] = acc; gbase[NB] = acc;
    off[NN] = NE;
  }
  __syncthreads();
  if (t < NB) {
    int g = gb[t];
    for (int r = 0; r < NBLK; ++r) poff[r * NB + t] += g;
  }
}

// Pass C: place packed pairs (src | dstlow<<17) at global bucket-contiguous slots
__global__ __launch_bounds__(256) void k_bin_place(const int* __restrict__ src,
                                                   const int* __restrict__ dst,
                                                   const int* __restrict__ poff,
                                                   uint32_t* __restrict__ pairbuf) {
  __shared__ int cur[NB];
  int t = threadIdx.x;
  if (t < NB) cur[t] = poff[blockIdx.x * NB + t];
  __syncthreads();
  int base = blockIdx.x * CHUNK;
  int end = min(base + CHUNK, NE);
  for (int i = base + t; i < end; i += 256) {
    int d = dst[i];
    int b = d >> BSH;
    int p = atomicAdd(&cur[b], 1);
    pairbuf[p] = (uint32_t)src[i] | ((uint32_t)(d & BMSK) << 17);
  }
}

// Pass D: per-bucket counting sort -> off[], inv[], csrs[]
__global__ __launch_bounds__(256) void k_bucket_sort(
    const uint32_t* __restrict__ pairbuf, const int* __restrict__ gbase,
    int* __restrict__ off, float* __restrict__ inv, int* __restrict__ csrs)
{
  __shared__ int cnt[512];
  __shared__ int loff[512];
  __shared__ int psum[256];
  int b = blockIdx.x;
  int tid = threadIdx.x;
  cnt[tid] = 0; cnt[tid + 256] = 0;
  __syncthreads();
  int s0 = gbase[b], s1 = gbase[b + 1];
  for (int i = s0 + tid; i < s1; i += 256)
    atomicAdd(&cnt[pairbuf[i] >> 17], 1);
  __syncthreads();
  // exclusive scan of 512 counters (pair-sums + Hillis-Steele over 256)
  int a0 = cnt[2 * tid], a1 = cnt[2 * tid + 1];
  int s = a0 + a1;
  psum[tid] = s;
  __syncthreads();
  for (int d = 1; d < 256; d <<= 1) {
    int v = (tid >= d) ? psum[tid - d] : 0;
    __syncthreads();
    psum[tid] += v;
    __syncthreads();
  }
  int excl = psum[tid] - s;
  loff[2 * tid] = excl;
  loff[2 * tid + 1] = excl + a0;
  __syncthreads();
  // node offsets + inv_sqrt(degree+1)
#pragma unroll
  for (int k = 0; k < 2; ++k) {
    int i = tid + k * 256;
    int node = b * 512 + i;
    if (node < NN) {
      off[node] = s0 + loff[i];
      inv[node] = rsqrtf((float)cnt[i] + 1.0f);
    }
  }
  __syncthreads();
  cnt[tid] = loff[tid]; cnt[tid + 256] = loff[tid + 256];  // counters -> cursors
  __syncthreads();
  for (int i = s0 + tid; i < s1; i += 256) {
    uint32_t v = pairbuf[i];
    int p = atomicAdd(&cnt[v >> 17], 1);
    csrs[s0 + p] = (int)(v & 0x1FFFFu);
  }
}

// ---------------- fp32 -> bf16 convert ----------------
__global__ void k_cvt(const float* __restrict__ x, uint16_t* __restrict__ xb) {
  size_t i = ((size_t)blockIdx.x * 256 + threadIdx.x) * 4;
  if (i >= (size_t)NN * HH) return;
  float4 v = *(const float4*)(x + i);
  uint2 o;
  o.x = f2b(v.x) | (f2b(v.y) << 16);
  o.y = f2b(v.z) | (f2b(v.w) << 16);
  *(uint2*)(xb + i) = o;
}

// ---------------- GEMM: Out[M,128] = bf16( A[M,128] @ W[128,128] + bias ) ----------------
__global__ __launch_bounds__(256) void k_gemm(
    const uint16_t* __restrict__ A, const float* __restrict__ W,
    const float* __restrict__ bias, uint16_t* __restrict__ Out,
    int M, int do_relu)
{
  __shared__ uint16_t Wt[128][136];   // W transposed: Wt[n][k], +8 pad
  const int tid = threadIdx.x;

  for (int it = 0; it < 16; ++it) {
    int idx = tid + it * 256;
    int n = idx & 127;
    int k0 = (idx >> 7) * 4;
    uint2 wv;
    wv.x = f2b(W[(k0 + 0) * 128 + n]) | (f2b(W[(k0 + 1) * 128 + n]) << 16);
    wv.y = f2b(W[(k0 + 2) * 128 + n]) | (f2b(W[(k0 + 3) * 128 + n]) << 16);
    *(uint2*)&Wt[n][k0] = wv;
  }
  __syncthreads();

  const int lane = tid & 63;
  const int wave = tid >> 6;
  const int lrow = lane & 15;
  const int lk = (lane >> 4) * 8;
  const int row0 = blockIdx.x * 128 + wave * 32;

  floatx4 acc[2][8];
#pragma unroll
  for (int t = 0; t < 2; ++t)
#pragma unroll
    for (int n = 0; n < 8; ++n)
      acc[t][n] = (floatx4){0.f, 0.f, 0.f, 0.f};

#pragma unroll
  for (int ks = 0; ks < 4; ++ks) {
    bf16x8 a[2];
#pragma unroll
    for (int t = 0; t < 2; ++t) {
      int r = row0 + t * 16 + lrow;
      uint4 tmp = {0u, 0u, 0u, 0u};
      if (r < M) tmp = *(const uint4*)(A + (size_t)r * HH + ks * 32 + lk);
      a[t] = __builtin_bit_cast(bf16x8, tmp);
    }
#pragma unroll
    for (int n = 0; n < 8; ++n) {
      bf16x8 b = __builtin_bit_cast(bf16x8, *(const uint4*)&Wt[n * 16 + lrow][ks * 32 + lk]);
      acc[0][n] = __builtin_amdgcn_mfma_f32_16x16x32_bf16(a[0], b, acc[0][n], 0, 0, 0);
      acc[1][n] = __builtin_amdgcn_mfma_f32_16x16x32_bf16(a[1], b, acc[1][n], 0, 0, 0);
    }
  }

  float bc[8];
#pragma unroll
  for (int n = 0; n < 8; ++n) bc[n] = bias[n * 16 + lrow];

  const int rbase = (lane >> 4) * 4;
#pragma unroll
  for (int t = 0; t < 2; ++t) {
#pragma unroll
    for (int r = 0; r < 4; ++r) {
      int row = row0 + t * 16 + rbase + r;
      if (row < M) {
#pragma unroll
        for (int n = 0; n < 8; ++n) {
          float v = acc[t][n][r] + bc[n];
          if (do_relu) v = fmaxf(v, 0.f);
          Out[(size_t)row * HH + n * 16 + lrow] = (uint16_t)f2b(v);
        }
      }
    }
  }
}

// ---------------- aggregation: h'[i] = inv[i]*( sum_e inv[src]*hw[src] ) + inv[i]^2*hw[i] ----------------
__global__ __launch_bounds__(256) void k_agg(
    const uint16_t* __restrict__ hw, const int* __restrict__ off,
    const int* __restrict__ csrs, const float* __restrict__ inv,
    uint16_t* __restrict__ hout, int do_relu)
{
  int node = blockIdx.x * 8 + (threadIdx.x >> 5);
  if (node >= NN) return;
  int c = (threadIdx.x & 31) * 4;

  float invd = inv[node];

  const uint2* sp = (const uint2*)(hw + (size_t)node * HH + c);
  uint2 sv = *sp;
  float a0 = invd * b2f(sv.x & 0xFFFFu);
  float a1 = invd * b2f(sv.x >> 16);
  float a2 = invd * b2f(sv.y & 0xFFFFu);
  float a3 = invd * b2f(sv.y >> 16);

  int e0 = off[node], e1 = off[node + 1];
  for (int e = e0; e < e1; ++e) {
    int s = csrs[e];
    float w = inv[s];
    uint2 v = *(const uint2*)(hw + (size_t)s * HH + c);
    a0 += w * b2f(v.x & 0xFFFFu);
    a1 += w * b2f(v.x >> 16);
    a2 += w * b2f(v.y & 0xFFFFu);
    a3 += w * b2f(v.y >> 16);
  }
  a0 *= invd; a1 *= invd; a2 *= invd; a3 *= invd;
  if (do_relu) {
    a0 = fmaxf(a0, 0.f); a1 = fmaxf(a1, 0.f);
    a2 = fmaxf(a2, 0.f); a3 = fmaxf(a3, 0.f);
  }
  uint2 o;
  o.x = f2b(a0) | (f2b(a1) << 16);
  o.y = f2b(a2) | (f2b(a3) << 16);
  *(uint2*)(hout + (size_t)node * HH + c) = o;
}

// ---------------- global add pool over sorted batch ids ----------------
__global__ void k_pool(const uint16_t* __restrict__ h, const int* __restrict__ batch,
                       float* __restrict__ pooled) {
  const int PCHUNK = 256;
  int c = threadIdx.x;   // 128 threads, one channel each
  int i0 = blockIdx.x * PCHUNK;
  if (i0 >= NN) return;
  int iend = min(i0 + PCHUNK, NN);
  float acc = 0.f;
  int g = batch[i0];
  for (int i = i0; i < iend; ++i) {
    int gi = batch[i];
    if (gi != g) {
      atomicAdd(&pooled[g * HH + c], acc);
      acc = 0.f;
      g = gi;
    }
    acc += b2f((uint32_t)h[(size_t)i * HH + c]);
  }
  atomicAdd(&pooled[g * HH + c], acc);
}

// ---------------- decoder ----------------
__global__ void k_dec(const float* __restrict__ pooled,
                      const float* __restrict__ w1, const float* __restrict__ b1,
                      const float* __restrict__ w2, const float* __restrict__ b2,
                      float* __restrict__ out) {
  __shared__ float p[128], t[128];
  int g = blockIdx.x, j = threadIdx.x;
  p[j] = pooled[g * HH + j];
  __syncthreads();
  float a = b1[j];
  for (int k = 0; k < 128; ++k) a += p[k] * w1[k * 128 + j];
  t[j] = fmaxf(a, 0.f);
  __syncthreads();
  if (j < 10) {
    float o = b2[j];
    for (int k = 0; k < 128; ++k) o += t[k] * w2[k * 10 + j];
    out[g * 10 + j] = o;
  }
}

extern "C" void kernel_launch(void* const* d_in, const int* in_sizes, int n_in,
                              void* d_out, int out_size, void* d_ws, size_t ws_size,
                              hipStream_t stream) {
  const float* x       = (const float*)d_in[0];
  const int*   eidx    = (const int*)d_in[1];
  const int*   src     = eidx;            // edge_index[0]
  const int*   dst     = eidx + NE;       // edge_index[1]
  const int*   batch   = (const int*)d_in[3];
  const float* enc_w1  = (const float*)d_in[4];
  const float* enc_b1  = (const float*)d_in[5];
  const float* enc_w2  = (const float*)d_in[6];
  const float* enc_b2  = (const float*)d_in[7];
  const float* conv_w  = (const float*)d_in[8];
  const float* conv_b  = (const float*)d_in[9];
  const float* dec_w1  = (const float*)d_in[10];
  const float* dec_b1  = (const float*)d_in[11];
  const float* dec_w2  = (const float*)d_in[12];
  const float* dec_b2  = (const float*)d_in[13];
  float* out = (float*)d_out;

  char* ws = (char*)d_ws;
  size_t o = 0;
  auto alloc = [&](size_t bytes) -> char* {
    char* p = ws + o;
    o += (bytes + 255) & ~(size_t)255;
    return p;
  };
  int*      off    = (int*)alloc((size_t)(NN + 1) * 4);
  int*      csrs   = (int*)alloc((size_t)NE * 4);
  float*    inv    = (float*)alloc((size_t)NN * 4);
  float*    pooled = (float*)alloc((size_t)NG * HH * 4);
  int*      blkcnt = (int*)alloc((size_t)NBLK * NB * 4);
  int*      poff   = (int*)alloc((size_t)NBLK * NB * 4);
  int*      gbase  = (int*)alloc((size_t)(NB + 1) * 4);
  uint16_t* buf0   = (uint16_t*)alloc((size_t)NN * HH * 2);
  uint16_t* buf1   = (uint16_t*)alloc((size_t)NN * HH * 2);
  uint32_t* pairbuf = (uint32_t*)buf1;    // alias: dead until encoder runs

  hipMemsetAsync(pooled, 0, (size_t)NG * HH * 4, stream);

  // CSR build: binned counting sort (all before encoder; pairbuf aliases buf1)
  k_bin_count<<<dim3(NBLK), dim3(256), 0, stream>>>(dst, blkcnt);
  k_btable<<<dim3(1), dim3(256), 0, stream>>>(blkcnt, poff, gbase, off);
  k_bin_place<<<dim3(NBLK), dim3(256), 0, stream>>>(src, dst, poff, pairbuf);
  k_bucket_sort<<<dim3(NB), dim3(256), 0, stream>>>(pairbuf, gbase, off, inv, csrs);

  // encoder
  k_cvt<<<dim3((NN * HH / 4 + 255) / 256), dim3(256), 0, stream>>>(x, buf0);
  const int GB = (NN + 127) / 128;   // 782
  k_gemm<<<dim3(GB), dim3(256), 0, stream>>>(buf0, enc_w1, enc_b1, buf1, NN, 1);
  k_gemm<<<dim3(GB), dim3(256), 0, stream>>>(buf1, enc_w2, enc_b2, buf0, NN, 0);

  // 3 GCN layers: gemm (b0->b1) then aggregate (b1->b0)
  k_gemm<<<dim3(GB), dim3(256), 0, stream>>>(buf0, conv_w + 0 * 16384, conv_b + 0,   buf1, NN, 0);
  k_agg <<<dim3((NN + 7) / 8), dim3(256), 0, stream>>>(buf1, off, csrs, inv, buf0, 1);
  k_gemm<<<dim3(GB), dim3(256), 0, stream>>>(buf0, conv_w + 1 * 16384, conv_b + 128, buf1, NN, 0);
  k_agg <<<dim3((NN + 7) / 8), dim3(256), 0, stream>>>(buf1, off, csrs, inv, buf0, 1);
  k_gemm<<<dim3(GB), dim3(256), 0, stream>>>(buf0, conv_w + 2 * 16384, conv_b + 256, buf1, NN, 0);
  k_agg <<<dim3((NN + 7) / 8), dim3(256), 0, stream>>>(buf1, off, csrs, inv, buf0, 0);

  // pool + decoder
  k_pool<<<dim3((NN + 255) / 256), dim3(128), 0, stream>>>(buf0, batch, pooled);
  k_dec<<<dim3(NG), dim3(128), 0, stream>>>(pooled, dec_w1, dec_b1, dec_w2, dec_b2, out);
}